// Round 1
// baseline (690.157 us; speedup 1.0000x reference)
//
#include <hip/hip_runtime.h>

#define T       2048
#define FEAT    1024
#define BTOT    64
#define BHALF   32
#define KSEL    20

// ---------------------------------------------------------------------------
// Kernel A: per-(b,t) magnitude (numpy-pairwise-exact) -> dropout-masked key
// One wave (64 lanes) per row of 1024 floats.
// numpy pairwise for n=1024: 8 blocks of 128; block = 8 accumulators r[j],
// each a sequential chain of 16 products; block tree ((r0+r1)+(r2+r3))+((r4+r5)+(r6+r7));
// top tree ((B0+B1)+(B2+B3))+((B4+B5)+(B6+B7)).
// Lane l = (B=l>>3, j=l&7) owns chain elements x[128B + 8i + j], i=0..15.
// xor-shuffle butterfly reproduces both trees bit-exactly (fp add is commutative).
// ---------------------------------------------------------------------------
__global__ __launch_bounds__(256) void mag_key_kernel(
        const float* __restrict__ feat,
        const float* __restrict__ mask_abn,
        const float* __restrict__ mask_nor,
        float* __restrict__ keys)
{
#pragma clang fp contract(off)
    const int row  = blockIdx.x * 4 + (threadIdx.x >> 6);   // 0 .. 64*2048-1
    const int lane = threadIdx.x & 63;
    const float* __restrict__ x = feat + (size_t)row * FEAT;

    const int B = lane >> 3;
    const int j = lane & 7;
    const int base = B * 128 + j;

    float v = x[base];
    float acc = v * v;                         // r[j] = a[j]
#pragma unroll
    for (int i = 1; i < 16; ++i) {             // 15 sequential adds, numpy order
        float w = x[base + 8 * i];
        float p = w * w;
        acc = acc + p;
    }
    // block tree: ((r0+r1)+(r2+r3))+((r4+r5)+(r6+r7))
    acc = acc + __shfl_xor(acc, 1);
    acc = acc + __shfl_xor(acc, 2);
    acc = acc + __shfl_xor(acc, 4);
    // top tree over 8 blocks of 128
    acc = acc + __shfl_xor(acc, 8);
    acc = acc + __shfl_xor(acc, 16);
    acc = acc + __shfl_xor(acc, 32);

    if (lane == 0) {
        float mag = sqrtf(acc);                // IEEE-correct sqrt (default on hipcc)
        int b = row >> 11;
        int t = row & (T - 1);
        float m = (b < BHALF) ? mask_nor[b * T + t]
                              : mask_abn[(b - BHALF) * T + t];
        // drop = (mask > 0.1f) ? 1.0f/0.9f : 0 ; key = mag * drop (fp32, like numpy)
        float key = (m > 0.1f) ? (mag * (1.0f / 0.9f)) : 0.0f;
        keys[row] = key;
    }
}

// ---------------------------------------------------------------------------
// Kernel B: per-batch-row top-20 (descending, ties -> lowest index), plus
// score mean in numpy n=20 pairwise order. One 256-thread block per row.
// ---------------------------------------------------------------------------
__global__ __launch_bounds__(256) void topk_kernel(
        const float* __restrict__ keys,
        const float* __restrict__ scores,
        int* __restrict__ sel_idx,
        float* __restrict__ out)
{
#pragma clang fp contract(off)
    const int b   = blockIdx.x;            // 0..63
    const int tid = threadIdx.x;
    const int lane = tid & 63;
    const int wid  = tid >> 6;

    __shared__ float skey[T];
    __shared__ unsigned long long wmax[4];
    __shared__ int s_sel[KSEL];

    for (int i = tid; i < T; i += 256) skey[i] = keys[b * T + i];
    __syncthreads();

    for (int k = 0; k < KSEL; ++k) {
        unsigned long long best = 0ull;
        for (int i = tid; i < T; i += 256) {
            float v = skey[i];
            if (v >= 0.0f) {   // skip already-selected (marked -1.0f)
                unsigned long long p =
                    ((unsigned long long)__float_as_uint(v) << 32) |
                    (unsigned long long)(0xFFFFFFFFu - (unsigned)i);
                if (p > best) best = p;
            }
        }
        // wave max
        #pragma unroll
        for (int d = 1; d < 64; d <<= 1) {
            unsigned long long o = __shfl_xor(best, d);
            if (o > best) best = o;
        }
        if (lane == 0) wmax[wid] = best;
        __syncthreads();
        if (tid == 0) {
            unsigned long long g = wmax[0];
            for (int w = 1; w < 4; ++w) if (wmax[w] > g) g = wmax[w];
            int idx = (int)(0xFFFFFFFFu - (unsigned)(g & 0xFFFFFFFFull));
            s_sel[k] = idx;
            skey[idx] = -1.0f;     // remove from candidates
        }
        __syncthreads();
    }

    if (tid == 0) {
        // numpy pairwise sum, n=20: r[0..7]=a[0..7]; r[j]+=a[8+j];
        // tree; then += a[16..19] sequentially; mean = sum / 20
        float a[KSEL];
        for (int k = 0; k < KSEL; ++k) a[k] = scores[b * T + s_sel[k]];
        float r[8];
        for (int jj = 0; jj < 8; ++jj) r[jj] = a[jj];
        for (int jj = 0; jj < 8; ++jj) r[jj] = r[jj] + a[8 + jj];
        float res = ((r[0] + r[1]) + (r[2] + r[3])) + ((r[4] + r[5]) + (r[6] + r[7]));
        res = res + a[16];
        res = res + a[17];
        res = res + a[18];
        res = res + a[19];
        float mean = res / 20.0f;
        // outputs: score_abnormal (b in [32,64) -> b-32), then score_normal (32 + b)
        int o = (b >= BHALF) ? (b - BHALF) : (BHALF + b);
        out[o] = mean;
    }
    if (tid < KSEL) sel_idx[b * KSEL + tid] = s_sel[tid];
}

// ---------------------------------------------------------------------------
// Kernel C: gather selected feature rows (exact fp32 copies).
// grid (20, 64); 256 threads x float4 = 4 KB per block.
// ---------------------------------------------------------------------------
__global__ __launch_bounds__(256) void gather_kernel(
        const float* __restrict__ feat,
        const int* __restrict__ sel_idx,
        float* __restrict__ out)
{
    const int k = blockIdx.x;   // 0..19
    const int b = blockIdx.y;   // 0..63
    const int t = sel_idx[b * KSEL + k];
    const float4* __restrict__ src =
        (const float4*)(feat + ((size_t)b * T + (size_t)t) * FEAT);
    size_t off;
    if (b >= BHALF) {   // abnormal block comes first in the output
        off = 64 + ((size_t)(b - BHALF) * KSEL + k) * FEAT;
    } else {
        off = 64 + (size_t)BHALF * KSEL * FEAT + ((size_t)b * KSEL + k) * FEAT;
    }
    float4* __restrict__ dst = (float4*)(out + off);
    dst[threadIdx.x] = src[threadIdx.x];
}

extern "C" void kernel_launch(void* const* d_in, const int* in_sizes, int n_in,
                              void* d_out, int out_size, void* d_ws, size_t ws_size,
                              hipStream_t stream)
{
    const float* feat   = (const float*)d_in[0];   // (64,2048,1024)
    const float* scores = (const float*)d_in[1];   // (64,2048,1)
    const float* mabn   = (const float*)d_in[2];   // (32,2048)
    const float* mnor   = (const float*)d_in[3];   // (32,2048)
    float* out = (float*)d_out;

    float* keys = (float*)d_ws;                            // 64*2048 floats = 512 KB
    int*   sel  = (int*)((char*)d_ws + (size_t)BTOT * T * sizeof(float)); // 64*20 ints

    // A: 64*2048 rows, one wave each, 4 rows per 256-thread block
    mag_key_kernel<<<(BTOT * T) / 4, 256, 0, stream>>>(feat, mabn, mnor, keys);
    // B: one block per batch row
    topk_kernel<<<BTOT, 256, 0, stream>>>(keys, scores, sel, out);
    // C: gather 64*20 rows of 1024 floats
    gather_kernel<<<dim3(KSEL, BTOT), 256, 0, stream>>>(feat, sel, out);
}

// Round 2
// 687.835 us; speedup vs baseline: 1.0034x; 1.0034x over previous
//
#include <hip/hip_runtime.h>

#define T       2048
#define FEAT    1024
#define BTOT    64
#define BHALF   32
#define KSEL    20

// ---------------------------------------------------------------------------
// Kernel A v2: per-(b,t) magnitude (numpy-pairwise-exact) -> dropout-masked key.
// One wave per row. Row staged through LDS with dense float4 global loads
// (64 lanes x 16 B = 1 KB/instr, perfectly coalesced), then the numpy chain
// reads come from LDS. LDS layout pads +4 floats per 128-float block so the
// strided chain reads are only 2-way bank conflicts (free on gfx950).
//
// numpy pairwise n=1024: 8 leaf blocks of 128; leaf = 8 accumulators r[j],
// r[j] = sequential sum of x[128B+8i+j]^2, i=0..15; leaf tree
// ((r0+r1)+(r2+r3))+((r4+r5)+(r6+r7)); top tree ((B0+B1)+(B2+B3))+((B4+B5)+(B6+B7)).
// Lane l = (B=l>>3, j=l&7); xor-butterfly 1,2,4 = leaf tree, 8,16,32 = top tree.
// ---------------------------------------------------------------------------
__global__ __launch_bounds__(256) void mag_key_kernel(
        const float* __restrict__ feat,
        const float* __restrict__ mask_abn,
        const float* __restrict__ mask_nor,
        float* __restrict__ keys)
{
#pragma clang fp contract(off)
    const int wid  = threadIdx.x >> 6;
    const int lane = threadIdx.x & 63;
    const int row  = blockIdx.x * 4 + wid;            // 0 .. 64*2048-1

    // 1024 floats + 4 pad per 128-float block = 1056 floats per wave
    __shared__ float sh[4 * 1056];
    float* lds = sh + wid * 1056;

    // ---- stage: dense float4 loads, padded LDS writes (conflict-free) ----
    const float4* __restrict__ src = (const float4*)(feat + (size_t)row * FEAT);
#pragma unroll
    for (int it = 0; it < 4; ++it) {
        int f = it * 64 + lane;                       // float4 index 0..255
        float4 v = src[f];
        int d = f * 4 + 4 * (f >> 5);                 // +4 floats per 128-float block
        *(float4*)(lds + d) = v;
    }
    __syncthreads();

    // ---- numpy-exact chain from LDS ----
    const int B = lane >> 3;
    const int j = lane & 7;
    const int base = B * 132 + j;                     // 132 = 128 + 4 pad

    float v0 = lds[base];
    float acc = v0 * v0;
#pragma unroll
    for (int i = 1; i < 16; ++i) {
        float w = lds[base + 8 * i];
        float p = w * w;
        acc = acc + p;
    }
    // leaf tree then top tree (fp add commutative -> butterfly is bit-exact)
    acc = acc + __shfl_xor(acc, 1);
    acc = acc + __shfl_xor(acc, 2);
    acc = acc + __shfl_xor(acc, 4);
    acc = acc + __shfl_xor(acc, 8);
    acc = acc + __shfl_xor(acc, 16);
    acc = acc + __shfl_xor(acc, 32);

    if (lane == 0) {
        float mag = sqrtf(acc);
        int b = row >> 11;
        int t = row & (T - 1);
        float m = (b < BHALF) ? mask_nor[b * T + t]
                              : mask_abn[(b - BHALF) * T + t];
        float key = (m > 0.1f) ? (mag * (1.0f / 0.9f)) : 0.0f;
        keys[row] = key;
    }
}

// ---------------------------------------------------------------------------
// Kernel B v2: per-batch-row top-20 (descending, ties -> lowest index).
// Candidates live in 8 packed u64 registers per thread (no per-round LDS scan).
// One barrier per round via double-buffered cross-wave max. Plus numpy n=20
// pairwise mean of the selected scores.
// ---------------------------------------------------------------------------
__global__ __launch_bounds__(256) void topk_kernel(
        const float* __restrict__ keys,
        const float* __restrict__ scores,
        int* __restrict__ sel_idx,
        float* __restrict__ out)
{
#pragma clang fp contract(off)
    const int b    = blockIdx.x;           // 0..63
    const int tid  = threadIdx.x;
    const int lane = tid & 63;
    const int wid  = tid >> 6;

    __shared__ unsigned long long wmax[2][4];
    __shared__ int s_sel[KSEL];

    // candidate i = tid + 256*s ; pack (key_bits<<32) | (~idx)
    unsigned long long p[8];
#pragma unroll
    for (int s = 0; s < 8; ++s) {
        int i = tid + 256 * s;
        float v = keys[b * T + i];
        p[s] = ((unsigned long long)__float_as_uint(v) << 32) |
               (unsigned long long)(0xFFFFFFFFu - (unsigned)i);
        // keys are >= 0 (mag*drop), so u32 float compare == float compare
    }

    int sel_local[KSEL];

    for (int k = 0; k < KSEL; ++k) {
        unsigned long long best = 0ull;
#pragma unroll
        for (int s = 0; s < 8; ++s)
            if (p[s] > best) best = p[s];
#pragma unroll
        for (int d = 1; d < 64; d <<= 1) {
            unsigned long long o = __shfl_xor(best, d);
            if (o > best) best = o;
        }
        if (lane == 0) wmax[k & 1][wid] = best;
        __syncthreads();
        unsigned long long g = wmax[k & 1][0];
#pragma unroll
        for (int w = 1; w < 4; ++w)
            if (wmax[k & 1][w] > g) g = wmax[k & 1][w];
        int idx = (int)(0xFFFFFFFFu - (unsigned)(g & 0xFFFFFFFFull));
        sel_local[k] = idx;
        // owner clears its candidate
        if ((idx & 255) == tid) p[idx >> 8] = 0ull;
    }

    if (tid == 0) {
        // numpy pairwise sum, n=20
        float a[KSEL];
        for (int k = 0; k < KSEL; ++k) a[k] = scores[b * T + sel_local[k]];
        float r[8];
        for (int jj = 0; jj < 8; ++jj) r[jj] = a[jj];
        for (int jj = 0; jj < 8; ++jj) r[jj] = r[jj] + a[8 + jj];
        float res = ((r[0] + r[1]) + (r[2] + r[3])) + ((r[4] + r[5]) + (r[6] + r[7]));
        res = res + a[16];
        res = res + a[17];
        res = res + a[18];
        res = res + a[19];
        float mean = res / 20.0f;
        int o = (b >= BHALF) ? (b - BHALF) : (BHALF + b);
        out[o] = mean;
    }
    if (tid < KSEL) sel_idx[b * KSEL + tid] = sel_local[tid];
}

// ---------------------------------------------------------------------------
// Kernel C: gather selected feature rows (exact fp32 copies).
// grid (20, 64); 256 threads x float4 = 4 KB per block.
// ---------------------------------------------------------------------------
__global__ __launch_bounds__(256) void gather_kernel(
        const float* __restrict__ feat,
        const int* __restrict__ sel_idx,
        float* __restrict__ out)
{
    const int k = blockIdx.x;   // 0..19
    const int b = blockIdx.y;   // 0..63
    const int t = sel_idx[b * KSEL + k];
    const float4* __restrict__ src =
        (const float4*)(feat + ((size_t)b * T + (size_t)t) * FEAT);
    size_t off;
    if (b >= BHALF) {   // abnormal block first in output
        off = 64 + ((size_t)(b - BHALF) * KSEL + k) * FEAT;
    } else {
        off = 64 + (size_t)BHALF * KSEL * FEAT + ((size_t)b * KSEL + k) * FEAT;
    }
    float4* __restrict__ dst = (float4*)(out + off);
    dst[threadIdx.x] = src[threadIdx.x];
}

extern "C" void kernel_launch(void* const* d_in, const int* in_sizes, int n_in,
                              void* d_out, int out_size, void* d_ws, size_t ws_size,
                              hipStream_t stream)
{
    const float* feat   = (const float*)d_in[0];   // (64,2048,1024)
    const float* scores = (const float*)d_in[1];   // (64,2048,1)
    const float* mabn   = (const float*)d_in[2];   // (32,2048)
    const float* mnor   = (const float*)d_in[3];   // (32,2048)
    float* out = (float*)d_out;

    float* keys = (float*)d_ws;                            // 64*2048 floats
    int*   sel  = (int*)((char*)d_ws + (size_t)BTOT * T * sizeof(float));

    mag_key_kernel<<<(BTOT * T) / 4, 256, 0, stream>>>(feat, mabn, mnor, keys);
    topk_kernel<<<BTOT, 256, 0, stream>>>(keys, scores, sel, out);
    gather_kernel<<<dim3(KSEL, BTOT), 256, 0, stream>>>(feat, sel, out);
}